// Round 7
// baseline (305.272 us; speedup 1.0000x reference)
//
#include <hip/hip_runtime.h>
#include <stdint.h>

#define LOG2E 1.4426950408889634f

typedef __bf16 v8bf __attribute__((ext_vector_type(8)));
typedef float v16f __attribute__((ext_vector_type(16)));

static constexpr int B = 4, N = 2048, FIN = 128, H = 4, DK = 32;
static constexpr int IT = N / 32;   // 64 i-tiles

__device__ __forceinline__ float exp2_fast(float x) {
#if __has_builtin(__builtin_amdgcn_exp2f)
  return __builtin_amdgcn_exp2f(x);
#else
  float r;
  asm("v_exp_f32 %0, %1" : "=v"(r) : "v"(x));
  return r;
#endif
}

__device__ __forceinline__ unsigned int bf16_rne(float f) {
  unsigned int u = __builtin_bit_cast(unsigned int, f);
  u += 0x7FFFu + ((u >> 16) & 1u);
  return u >> 16;
}

// pack 8 floats -> v8bf (RNE)
__device__ __forceinline__ v8bf pack8(const float* v) {
  uint4 u;
  u.x = bf16_rne(v[0]) | (bf16_rne(v[1]) << 16);
  u.y = bf16_rne(v[2]) | (bf16_rne(v[3]) << 16);
  u.z = bf16_rne(v[4]) | (bf16_rne(v[5]) << 16);
  u.w = bf16_rne(v[6]) | (bf16_rne(v[7]) << 16);
  return __builtin_bit_cast(v8bf, u);
}

// ---------------- kernel 1: h projection via MFMA (f32 in, casts fused) ----------------
__global__ __launch_bounds__(256) void k_hproj(const float* __restrict__ x,
                                               const float* __restrict__ W,
                                               const float* __restrict__ a,
                                               unsigned short* __restrict__ h_t,
                                               float* __restrict__ el,
                                               float* __restrict__ er) {
  int blk = blockIdx.x;
  int b = blk >> 6, it = blk & 63;
  int tid = threadIdx.x;
  int head = tid >> 6, lane = tid & 63;
  int lrow = lane & 31, kh = lane >> 5;
  int bh = b * H + head;
  int n = it * 32 + lrow;
  const float* xp = x + (b * N + n) * FIN + kh * 8;
  const float* wp = W + head * FIN * DK + lrow;
  v16f acc = {};
#pragma unroll
  for (int s = 0; s < FIN / 16; ++s) {
    float xv[8], wv[8];
    *(float4*)&xv[0] = *(const float4*)(xp + s * 16);
    *(float4*)&xv[4] = *(const float4*)(xp + s * 16 + 4);
    int fb = s * 16 + kh * 8;
#pragma unroll
    for (int k = 0; k < 8; ++k) wv[k] = wp[(fb + k) * DK];
    acc = __builtin_amdgcn_mfma_f32_32x32x16_bf16(pack8(wv), pack8(xv), acc, 0, 0, 0);
  }
  float pel = 0.f, per = 0.f;
#pragma unroll
  for (int r = 0; r < 16; ++r) {
    int d = (r & 3) + 8 * (r >> 2) + 4 * kh;   // C/D row mapping (32x32 bf16)
    float hv = acc[r];
    h_t[(bh * DK + d) * N + n] = (unsigned short)bf16_rne(hv);
    pel = fmaf(hv, a[head * 2 * DK + d], pel);
    per = fmaf(hv, a[head * 2 * DK + DK + d], per);
  }
  pel += __shfl_xor(pel, 32);
  per += __shfl_xor(per, 32);
  if (kh == 0) {
    el[bh * N + n] = pel * LOG2E;
    er[bh * N + n] = per * LOG2E;
  }
}

// ---------------- kernel 2: fused attention partials (raw adj) ----------------
// block = (b, it, jh): 512 blocks x 1024 threads = 16 waves = head(4) x jq(4).
// Each wave: 256 j of its j-half as dual 128-j streams. 2 blocks/CU -> 32 waves/CU.
__global__ __launch_bounds__(1024, 8) void k_attn(const int* __restrict__ adj,
                                                  const unsigned short* __restrict__ h_t,
                                                  const float* __restrict__ el,
                                                  const float* __restrict__ er,
                                                  float* __restrict__ pnum,
                                                  float* __restrict__ pl) {
  __shared__ float ersh[H * 1024];  // 16 KB: er[head][j-half]
  __shared__ float part[H * 1024];  // 16 KB: [head][i*32+d]
  __shared__ float lsh[H * 32];     // [head][i]
  int blk = blockIdx.x;
  int jh = blk & 1;
  int tile = blk >> 1;              // b*IT+it
  int b = tile >> 6, it = tile & 63;
  int tid = threadIdx.x;
  int wave = tid >> 6;
  int head = wave & 3, jq = wave >> 2;
  int lane = tid & 63, lrow = lane & 31, kh = lane >> 5;
  int ig = it * 32 + lrow, bh = b * H + head;

  {  // cooperative er load: 4 heads x 1024 j = 1024 float4
    int hh = tid >> 8;
    const float4* es = (const float4*)(er + (b * H + hh) * N + jh * 1024);
    ((float4*)ersh)[tid] = es[tid & 255];
  }
  part[tid] = 0.f;
  part[tid + 1024] = 0.f;
  part[tid + 2048] = 0.f;
  part[tid + 3072] = 0.f;
  if (tid < H * 32) lsh[tid] = 0.f;
  __syncthreads();

  float eli = el[bh * N + ig];
  int j0 = jh * 1024 + jq * 256 + kh * 8;
  const int* arow = adj + (size_t)(b * N + ig) * N + j0;
  const unsigned short* hp = h_t + (size_t)(bh * DK + lrow) * N + j0;
  const float* ep = ersh + head * 1024 + jq * 256 + kh * 8;

  v16f acc0 = {}, acc1 = {};
  float ls0 = 0.f, ls1 = 0.f;

  // depth-1 prefetch per stream; stream1 covers +128 j
  int4 A0a = *(const int4*)(arow);
  int4 A0b = *(const int4*)(arow + 4);
  int4 H0 = *(const int4*)(hp);
  int4 A1a = *(const int4*)(arow + 128);
  int4 A1b = *(const int4*)(arow + 132);
  int4 H1 = *(const int4*)(hp + 128);

  auto step = [&](int4 aa, int4 ab, int4 hb, int eoff, v16f& acc, float& lsum) {
    float4 ea = *(const float4*)(ep + eoff);
    float4 eb = *(const float4*)(ep + eoff + 4);
    int ad[8] = {aa.x, aa.y, aa.z, aa.w, ab.x, ab.y, ab.z, ab.w};
    float ev[8] = {ea.x, ea.y, ea.z, ea.w, eb.x, eb.y, eb.z, eb.w};
    unsigned ub[8];
#pragma unroll
    for (int k = 0; k < 8; ++k) {
      float tt = eli + ev[k];
      tt = fmaxf(tt, 0.2f * tt);            // leaky relu (log2e pre-folded)
      float pv = exp2_fast(tt);
      unsigned u = __builtin_bit_cast(unsigned, pv) & 0xFFFF0000u;
      u = ad[k] ? u : 0u;                   // adjacency mask
      ub[k] = u;
      lsum += __builtin_bit_cast(float, u); // truncated: num/den consistent
    }
    unsigned u0 = __builtin_amdgcn_perm(ub[1], ub[0], 0x07060302u);
    unsigned u1 = __builtin_amdgcn_perm(ub[3], ub[2], 0x07060302u);
    unsigned u2 = __builtin_amdgcn_perm(ub[5], ub[4], 0x07060302u);
    unsigned u3 = __builtin_amdgcn_perm(ub[7], ub[6], 0x07060302u);
    uint4 au = {u0, u1, u2, u3};
    acc = __builtin_amdgcn_mfma_f32_32x32x16_bf16(
        __builtin_bit_cast(v8bf, au), __builtin_bit_cast(v8bf, hb), acc, 0, 0, 0);
  };

  for (int s = 0; s < 8; ++s) {
    int4 aa = A0a, ab = A0b, hb = H0;
    if (s + 1 < 8) {
      int o = (s + 1) * 16;
      A0a = *(const int4*)(arow + o);
      A0b = *(const int4*)(arow + o + 4);
      H0 = *(const int4*)(hp + o);
    }
    step(aa, ab, hb, s * 16, acc0, ls0);
    aa = A1a; ab = A1b; hb = H1;
    if (s + 1 < 8) {
      int o = 128 + (s + 1) * 16;
      A1a = *(const int4*)(arow + o);
      A1b = *(const int4*)(arow + o + 4);
      H1 = *(const int4*)(hp + o);
    }
    step(aa, ab, hb, 128 + s * 16, acc1, ls1);
  }

  float lsum = ls0 + ls1;
  lsum += __shfl_xor(lsum, 32);   // combine kh halves
  if (lane < 32) atomicAdd(&lsh[head * 32 + lane], lsum);
#pragma unroll
  for (int r = 0; r < 16; ++r) {
    int rowl = (r & 3) + 8 * (r >> 2) + 4 * kh;   // i-row within tile
    atomicAdd(&part[head * 1024 + rowl * 32 + lrow], acc0[r] + acc1[r]);
  }
  __syncthreads();

  // write block partials: 4096 num + 128 rowsums, coalesced
  float* pn = pnum + (size_t)blk * 4096;
  pn[tid] = part[tid];
  pn[tid + 1024] = part[tid + 1024];
  pn[tid + 2048] = part[tid + 2048];
  pn[tid + 3072] = part[tid + 3072];
  if (tid < 128) pl[blk * 128 + tid] = lsh[tid];
}

// ---------------- kernel 3: combine jh halves, divide, write out ----------------
__global__ __launch_bounds__(256) void k_comb(const float* __restrict__ pnum,
                                              const float* __restrict__ pl,
                                              float* __restrict__ out) {
  int g = blockIdx.x * 256 + threadIdx.x;   // float4 id
  int gd = g * 4;                           // ((b*H+head)*N + i)*DK + d
  int d = gd & 31;
  int i = (gd >> 5) & (N - 1);
  int head = (gd >> 16) & 3;
  int b = gd >> 18;
  int it = i >> 5, row = i & 31;
  int t2 = ((b * IT + it) << 1);            // block pair base
  int off = head * 1024 + row * 32 + d;
  float4 n0 = *(const float4*)(pnum + (size_t)t2 * 4096 + off);
  float4 n1 = *(const float4*)(pnum + (size_t)(t2 + 1) * 4096 + off);
  float l = pl[t2 * 128 + head * 32 + row] + pl[(t2 + 1) * 128 + head * 32 + row];
  float inv = 1.0f / l;
  float4 o = {(n0.x + n1.x) * inv, (n0.y + n1.y) * inv,
              (n0.z + n1.z) * inv, (n0.w + n1.w) * inv};
  *(float4*)(out + gd) = o;
}

extern "C" void kernel_launch(void* const* d_in, const int* in_sizes, int n_in,
                              void* d_out, int out_size, void* d_ws, size_t ws_size,
                              hipStream_t stream) {
  const float* x = (const float*)d_in[0];
  const int* adj = (const int*)d_in[1];
  const float* W = (const float*)d_in[2];
  const float* a = (const float*)d_in[3];
  float* out = (float*)d_out;
  char* ws = (char*)d_ws;

  unsigned short* h_t = (unsigned short*)(ws);   // 2 MB  [B][H][DK][N]
  float* el = (float*)(ws + 0x200000);           // 128 KB
  float* er = (float*)(ws + 0x220000);           // 128 KB
  float* pnum = (float*)(ws + 0x240000);         // 8 MB  [512][4096]
  float* pl = (float*)(ws + 0xA40000);           // 256 KB [512][128]

  hipLaunchKernelGGL(k_hproj, dim3(B * IT), dim3(256), 0, stream, x, W, a, h_t, el, er);
  hipLaunchKernelGGL(k_attn, dim3(B * IT * 2), dim3(1024), 0, stream, adj, h_t, el, er, pnum, pl);
  hipLaunchKernelGGL(k_comb, dim3(B * H * N * DK / 1024), dim3(256), 0, stream, pnum, pl, out);
}

// Round 8
// 157.614 us; speedup vs baseline: 1.9368x; 1.9368x over previous
//
#include <hip/hip_runtime.h>
#include <stdint.h>

#define LOG2E 1.4426950408889634f

typedef __bf16 v8bf __attribute__((ext_vector_type(8)));
typedef float v4f __attribute__((ext_vector_type(4)));
typedef float v16f __attribute__((ext_vector_type(16)));

static constexpr int B = 4, N = 2048, FIN = 128, H = 4, DK = 32;
static constexpr int IT = N / 32;   // 64 32-row i-tiles (k_hproj)

__device__ __forceinline__ float exp2_fast(float x) {
#if __has_builtin(__builtin_amdgcn_exp2f)
  return __builtin_amdgcn_exp2f(x);
#else
  float r;
  asm("v_exp_f32 %0, %1" : "=v"(r) : "v"(x));
  return r;
#endif
}

__device__ __forceinline__ unsigned int bf16_rne(float f) {
  unsigned int u = __builtin_bit_cast(unsigned int, f);
  u += 0x7FFFu + ((u >> 16) & 1u);
  return u >> 16;
}

// pack 8 floats -> v8bf (RNE)
__device__ __forceinline__ v8bf pack8(const float* v) {
  uint4 u;
  u.x = bf16_rne(v[0]) | (bf16_rne(v[1]) << 16);
  u.y = bf16_rne(v[2]) | (bf16_rne(v[3]) << 16);
  u.z = bf16_rne(v[4]) | (bf16_rne(v[5]) << 16);
  u.w = bf16_rne(v[6]) | (bf16_rne(v[7]) << 16);
  return __builtin_bit_cast(v8bf, u);
}

// ---------------- kernel 1: h projection via MFMA (f32 in, casts fused) ----------------
// (unchanged from R6 — validated numerics, ~7 us)
__global__ __launch_bounds__(256) void k_hproj(const float* __restrict__ x,
                                               const float* __restrict__ W,
                                               const float* __restrict__ a,
                                               unsigned short* __restrict__ h_t,
                                               float* __restrict__ el,
                                               float* __restrict__ er) {
  int blk = blockIdx.x;
  int b = blk >> 6, it = blk & 63;
  int tid = threadIdx.x;
  int head = tid >> 6, lane = tid & 63;
  int lrow = lane & 31, kh = lane >> 5;
  int bh = b * H + head;
  int n = it * 32 + lrow;
  const float* xp = x + (b * N + n) * FIN + kh * 8;
  const float* wp = W + head * FIN * DK + lrow;
  v16f acc = {};
#pragma unroll
  for (int s = 0; s < FIN / 16; ++s) {
    float xv[8], wv[8];
    *(float4*)&xv[0] = *(const float4*)(xp + s * 16);
    *(float4*)&xv[4] = *(const float4*)(xp + s * 16 + 4);
    int fb = s * 16 + kh * 8;
#pragma unroll
    for (int k = 0; k < 8; ++k) wv[k] = wp[(fb + k) * DK];
    acc = __builtin_amdgcn_mfma_f32_32x32x16_bf16(pack8(wv), pack8(xv), acc, 0, 0, 0);
  }
  float pel = 0.f, per = 0.f;
#pragma unroll
  for (int r = 0; r < 16; ++r) {
    int d = (r & 3) + 8 * (r >> 2) + 4 * kh;   // C/D row mapping (32x32 bf16)
    float hv = acc[r];
    h_t[(bh * DK + d) * N + n] = (unsigned short)bf16_rne(hv);
    pel = fmaf(hv, a[head * 2 * DK + d], pel);
    per = fmaf(hv, a[head * 2 * DK + DK + d], per);
  }
  pel += __shfl_xor(pel, 32);
  per += __shfl_xor(per, 32);
  if (kh == 0) {
    el[bh * N + n] = pel * LOG2E;
    er[bh * N + n] = per * LOG2E;
  }
}

// ---------------- kernel 2: fused attention, 16-row tiles, raw adj, direct out --------
// grid = B * 128 (16-row i-tiles); block = 1024 = 16 waves = head(4) x jq(4, 512 j).
// mfma_f32_16x16x32_bf16: A = P (m=lane&15, k=(lane>>4)*8+e); B = H (n=lane&15 -> d,
// k likewise); two d-blocks (d0=0,16) per wave -> 2 acc x 4 VGPR.
__global__ __launch_bounds__(1024, 6) void k_attn(const int* __restrict__ adj,
                                                  const unsigned short* __restrict__ h_t,
                                                  const float* __restrict__ el,
                                                  const float* __restrict__ er,
                                                  float* __restrict__ out) {
  __shared__ float ersh[H * N];        // 32 KB: er[head][j]
  __shared__ float part[H * 16 * DK];  // 8 KB: [head][i(16)][d(32)]
  __shared__ float lsh[H * 16];        // [head][i]
  int blk = blockIdx.x;
  int b = blk >> 7, it16 = blk & 127;
  int tid = threadIdx.x;
  int wave = tid >> 6;
  int head = wave & 3, jq = wave >> 2;
  int lane = tid & 63;
  int m = lane & 15, kg = lane >> 4;   // A row / B col; k-group 0..3
  int bh = b * H + head;
  int ig = it16 * 16 + m;

  {  // cooperative er load: 4 heads x 2048 floats = 2048 float4
    int hh = tid >> 8, t = tid & 255;
    const float4* es = (const float4*)(er + (b * H + hh) * N);
    float4* ed = (float4*)ersh;
    ed[hh * 512 + t] = es[t];
    ed[hh * 512 + 256 + t] = es[256 + t];
  }
  part[tid] = 0.f;
  part[tid + 1024] = 0.f;
  if (tid < H * 16) lsh[tid] = 0.f;
  __syncthreads();

  float eli = el[bh * N + ig];
  int j0 = jq * 512 + kg * 8;
  const int* arow = adj + (size_t)(b * N + ig) * N + j0;
  const unsigned short* hp0 = h_t + (size_t)(bh * DK + m) * N + j0;   // d = m
  const unsigned short* hp1 = hp0 + 16 * N;                           // d = m + 16
  const float* ep = ersh + head * N + j0;

  v4f acc0 = {}, acc1 = {};
  float lsum = 0.f;

  // depth-1 prefetch (TLP at 6-8 waves/SIMD carries the latency)
  int4 Aa = *(const int4*)(arow);
  int4 Ab = *(const int4*)(arow + 4);
  int4 Hb0 = *(const int4*)(hp0);
  int4 Hb1 = *(const int4*)(hp1);

  for (int s = 0; s < 16; ++s) {
    int4 aa = Aa, ab = Ab, h0 = Hb0, h1 = Hb1;
    if (s + 1 < 16) {
      int o = (s + 1) * 32;      // 32 j per step
      Aa = *(const int4*)(arow + o);
      Ab = *(const int4*)(arow + o + 4);
      Hb0 = *(const int4*)(hp0 + o);
      Hb1 = *(const int4*)(hp1 + o);
    }
    float4 ea = *(const float4*)(ep + s * 32);
    float4 eb = *(const float4*)(ep + s * 32 + 4);
    int ad[8] = {aa.x, aa.y, aa.z, aa.w, ab.x, ab.y, ab.z, ab.w};
    float ev[8] = {ea.x, ea.y, ea.z, ea.w, eb.x, eb.y, eb.z, eb.w};
    unsigned ub[8];
#pragma unroll
    for (int k = 0; k < 8; ++k) {
      float tt = eli + ev[k];
      tt = fmaxf(tt, 0.2f * tt);            // leaky relu (log2e pre-folded)
      float pv = exp2_fast(tt);
      unsigned u = __builtin_bit_cast(unsigned, pv) & 0xFFFF0000u;
      u = ad[k] ? u : 0u;                   // adjacency mask
      ub[k] = u;
      lsum += __builtin_bit_cast(float, u); // truncated: num/den consistent
    }
    unsigned u0 = __builtin_amdgcn_perm(ub[1], ub[0], 0x07060302u);
    unsigned u1 = __builtin_amdgcn_perm(ub[3], ub[2], 0x07060302u);
    unsigned u2 = __builtin_amdgcn_perm(ub[5], ub[4], 0x07060302u);
    unsigned u3 = __builtin_amdgcn_perm(ub[7], ub[6], 0x07060302u);
    uint4 au = {u0, u1, u2, u3};
    v8bf av = __builtin_bit_cast(v8bf, au);
    acc0 = __builtin_amdgcn_mfma_f32_16x16x32_bf16(av, __builtin_bit_cast(v8bf, h0),
                                                   acc0, 0, 0, 0);
    acc1 = __builtin_amdgcn_mfma_f32_16x16x32_bf16(av, __builtin_bit_cast(v8bf, h1),
                                                   acc1, 0, 0, 0);
  }

  // row sum for row m: combine the 4 k-groups (lanes m, m+16, m+32, m+48)
  lsum += __shfl_xor(lsum, 16);
  lsum += __shfl_xor(lsum, 32);
  if (lane < 16) atomicAdd(&lsh[head * 16 + lane], lsum);
  // C/D: col = lane&15 (d within block), row = kg*4 + reg (i within tile)
#pragma unroll
  for (int r = 0; r < 4; ++r) {
    int row = kg * 4 + r;
    atomicAdd(&part[(head * 16 + row) * DK + m], acc0[r]);
    atomicAdd(&part[(head * 16 + row) * DK + 16 + m], acc1[r]);
  }
  __syncthreads();

  // 2048 outputs: 512 threads x float4, coalesced
  if (tid < 512) {
    int gd = tid * 4;
    int rh = gd >> 9, ri = (gd >> 5) & 15, rd = gd & 31;
    float inv = 1.0f / lsh[rh * 16 + ri];
    float4 s4 = *(const float4*)&part[(rh * 16 + ri) * DK + rd];
    float4 o = {s4.x * inv, s4.y * inv, s4.z * inv, s4.w * inv};
    *(float4*)&out[(size_t)((b * H + rh) * N + it16 * 16 + ri) * DK + rd] = o;
  }
}

extern "C" void kernel_launch(void* const* d_in, const int* in_sizes, int n_in,
                              void* d_out, int out_size, void* d_ws, size_t ws_size,
                              hipStream_t stream) {
  const float* x = (const float*)d_in[0];
  const int* adj = (const int*)d_in[1];
  const float* W = (const float*)d_in[2];
  const float* a = (const float*)d_in[3];
  float* out = (float*)d_out;
  char* ws = (char*)d_ws;

  unsigned short* h_t = (unsigned short*)(ws);   // 2 MB  [B][H][DK][N]
  float* el = (float*)(ws + 0x200000);           // 128 KB
  float* er = (float*)(ws + 0x220000);           // 128 KB

  hipLaunchKernelGGL(k_hproj, dim3(B * IT), dim3(256), 0, stream, x, W, a, h_t, el, er);
  hipLaunchKernelGGL(k_attn, dim3(B * (N / 16)), dim3(1024), 0, stream, adj, h_t, el, er, out);
}

// Round 9
// 152.499 us; speedup vs baseline: 2.0018x; 1.0335x over previous
//
#include <hip/hip_runtime.h>
#include <stdint.h>

#define LOG2E 1.4426950408889634f

typedef __bf16 v8bf __attribute__((ext_vector_type(8)));
typedef float v4f __attribute__((ext_vector_type(4)));
typedef float v16f __attribute__((ext_vector_type(16)));

static constexpr int B = 4, N = 2048, FIN = 128, H = 4, DK = 32;
static constexpr int IT = N / 32;   // 64 32-row i-tiles (k_hproj)

__device__ __forceinline__ float exp2_fast(float x) {
#if __has_builtin(__builtin_amdgcn_exp2f)
  return __builtin_amdgcn_exp2f(x);
#else
  float r;
  asm("v_exp_f32 %0, %1" : "=v"(r) : "v"(x));
  return r;
#endif
}

__device__ __forceinline__ unsigned int bf16_rne(float f) {
  unsigned int u = __builtin_bit_cast(unsigned int, f);
  u += 0x7FFFu + ((u >> 16) & 1u);
  return u >> 16;
}

// pack 8 floats -> v8bf (RNE)
__device__ __forceinline__ v8bf pack8(const float* v) {
  uint4 u;
  u.x = bf16_rne(v[0]) | (bf16_rne(v[1]) << 16);
  u.y = bf16_rne(v[2]) | (bf16_rne(v[3]) << 16);
  u.z = bf16_rne(v[4]) | (bf16_rne(v[5]) << 16);
  u.w = bf16_rne(v[6]) | (bf16_rne(v[7]) << 16);
  return __builtin_bit_cast(v8bf, u);
}

// ---------------- kernel 0: bit-pack adjacency: adjb[b][i][j/32] ----------------
// wave packs 256 consecutive ints; rows never crossed (2048 % 256 == 0). BW-bound.
__global__ __launch_bounds__(256) void k_pack(const int* __restrict__ adj,
                                              unsigned int* __restrict__ adjb) {
  int wid = (blockIdx.x * 256 + threadIdx.x) >> 6;
  int lane = threadIdx.x & 63;
  const int* p = adj + (size_t)wid * 256 + lane;
  unsigned long long m0 = __ballot(p[0] != 0);
  unsigned long long m1 = __ballot(p[64] != 0);
  unsigned long long m2 = __ballot(p[128] != 0);
  unsigned long long m3 = __ballot(p[192] != 0);
  if (lane == 0) {
    uint4 v0 = {(unsigned)m0, (unsigned)(m0 >> 32), (unsigned)m1, (unsigned)(m1 >> 32)};
    uint4 v1 = {(unsigned)m2, (unsigned)(m2 >> 32), (unsigned)m3, (unsigned)(m3 >> 32)};
    uint4* dst = (uint4*)(adjb + (size_t)wid * 8);
    dst[0] = v0;
    dst[1] = v1;
  }
}

// ---------------- kernel 1: h projection via MFMA (f32 in, casts fused) ----------------
__global__ __launch_bounds__(256) void k_hproj(const float* __restrict__ x,
                                               const float* __restrict__ W,
                                               const float* __restrict__ a,
                                               unsigned short* __restrict__ h_t,
                                               float* __restrict__ el,
                                               float* __restrict__ er) {
  int blk = blockIdx.x;
  int b = blk >> 6, it = blk & 63;
  int tid = threadIdx.x;
  int head = tid >> 6, lane = tid & 63;
  int lrow = lane & 31, kh = lane >> 5;
  int bh = b * H + head;
  int n = it * 32 + lrow;
  const float* xp = x + (b * N + n) * FIN + kh * 8;
  const float* wp = W + head * FIN * DK + lrow;
  v16f acc = {};
#pragma unroll
  for (int s = 0; s < FIN / 16; ++s) {
    float xv[8], wv[8];
    *(float4*)&xv[0] = *(const float4*)(xp + s * 16);
    *(float4*)&xv[4] = *(const float4*)(xp + s * 16 + 4);
    int fb = s * 16 + kh * 8;
#pragma unroll
    for (int k = 0; k < 8; ++k) wv[k] = wp[(fb + k) * DK];
    acc = __builtin_amdgcn_mfma_f32_32x32x16_bf16(pack8(wv), pack8(xv), acc, 0, 0, 0);
  }
  float pel = 0.f, per = 0.f;
#pragma unroll
  for (int r = 0; r < 16; ++r) {
    int d = (r & 3) + 8 * (r >> 2) + 4 * kh;   // C/D row mapping (32x32 bf16)
    float hv = acc[r];
    h_t[(bh * DK + d) * N + n] = (unsigned short)bf16_rne(hv);
    pel = fmaf(hv, a[head * 2 * DK + d], pel);
    per = fmaf(hv, a[head * 2 * DK + DK + d], per);
  }
  pel += __shfl_xor(pel, 32);
  per += __shfl_xor(per, 32);
  if (kh == 0) {
    el[bh * N + n] = pel * LOG2E;
    er[bh * N + n] = per * LOG2E;
  }
}

// ---------------- kernel 2: fused attention, 16-row tiles, bitmask in LDS ----------
// grid = B * 128; block = 1024 = 16 waves = head(4) x jq(4, 512 j each).
// All hot operands L2/LDS-resident: bitmask (LDS), er (LDS), h_t (L2, 2 MB).
// Denominator via 3rd MFMA with ones-column B: consumes the same packed A-frag
// as the numerator -> truncation-consistent, no per-k scalar adds.
__global__ __launch_bounds__(1024) void k_attn(const unsigned int* __restrict__ adjb,
                                               const unsigned short* __restrict__ h_t,
                                               const float* __restrict__ el,
                                               const float* __restrict__ er,
                                               float* __restrict__ out) {
  __shared__ float ersh[H * N];        // 32 KB: er[head][j]
  __shared__ float part[H * 16 * DK];  // 8 KB: [head][i(16)][d(32)]
  __shared__ float lsh[H * 16];        // [head][i]
  __shared__ unsigned amask[16 * 65];  // 4.2 KB: adj bits, padded stride 65
  int blk = blockIdx.x;
  int b = blk >> 7, it16 = blk & 127;
  int tid = threadIdx.x;
  int wave = tid >> 6;
  int head = wave & 3, jq = wave >> 2;
  int lane = tid & 63;
  int m = lane & 15, kg = lane >> 4;   // A/B row-col; k-group 0..3
  int bh = b * H + head;
  int ig = it16 * 16 + m;

  {  // cooperative er load: 4 heads x 2048 floats = 2048 float4
    int hh = tid >> 8, t = tid & 255;
    const float4* es = (const float4*)(er + (b * H + hh) * N);
    float4* ed = (float4*)ersh;
    ed[hh * 512 + t] = es[t];
    ed[hh * 512 + 256 + t] = es[256 + t];
  }
  // cooperative bitmask load: 16 rows x 64 dwords
  {
    int row = tid >> 6, dw = tid & 63;
    amask[row * 65 + dw] = adjb[(size_t)(b * N + it16 * 16 + row) * 64 + dw];
  }
  part[tid] = 0.f;
  part[tid + 1024] = 0.f;
  if (tid < H * 16) lsh[tid] = 0.f;
  __syncthreads();

  float eli = el[bh * N + ig];
  int j0 = jq * 512 + kg * 8;
  const unsigned short* hp0 = h_t + (size_t)(bh * DK + m) * N + j0;   // d = m
  const unsigned short* hp1 = hp0 + 16 * N;                           // d = m + 16
  const float* ep = ersh + head * N + j0;
  int shbase = kg * 8;

  // ones B-fragment: column n==0 only -> D[i][0] = row sum of A
  unsigned oc = (m == 0) ? 0x3F803F80u : 0u;
  uint4 ou = {oc, oc, oc, oc};
  v8bf ones_f = __builtin_bit_cast(v8bf, ou);

  v4f acc0 = {}, acc1 = {}, acc2 = {};

  // depth-1 prefetch on the (L2-hot) h stream
  int4 Hb0 = *(const int4*)(hp0);
  int4 Hb1 = *(const int4*)(hp1);

  for (int s = 0; s < 16; ++s) {
    int4 h0 = Hb0, h1 = Hb1;
    if (s + 1 < 16) {
      int o = (s + 1) * 32;      // 32 j per step
      Hb0 = *(const int4*)(hp0 + o);
      Hb1 = *(const int4*)(hp1 + o);
    }
    unsigned mdw = amask[m * 65 + jq * 16 + s];   // broadcast across kg (free)
    float4 ea = *(const float4*)(ep + s * 32);
    float4 eb = *(const float4*)(ep + s * 32 + 4);
    float ev[8] = {ea.x, ea.y, ea.z, ea.w, eb.x, eb.y, eb.z, eb.w};
    unsigned ub[8];
#pragma unroll
    for (int k = 0; k < 8; ++k) {
      float tt = eli + ev[k];
      tt = fmaxf(tt, 0.2f * tt);            // leaky relu (log2e pre-folded)
      float pv = exp2_fast(tt);
      unsigned bit = (mdw >> (shbase + k)) & 1u;
      ub[k] = __builtin_bit_cast(unsigned, pv) & (0u - bit);  // mask to +0
    }
    unsigned u0 = __builtin_amdgcn_perm(ub[1], ub[0], 0x07060302u);
    unsigned u1 = __builtin_amdgcn_perm(ub[3], ub[2], 0x07060302u);
    unsigned u2 = __builtin_amdgcn_perm(ub[5], ub[4], 0x07060302u);
    unsigned u3 = __builtin_amdgcn_perm(ub[7], ub[6], 0x07060302u);
    uint4 au = {u0, u1, u2, u3};
    v8bf av = __builtin_bit_cast(v8bf, au);   // truncated bf16 p-values
    acc0 = __builtin_amdgcn_mfma_f32_16x16x32_bf16(av, __builtin_bit_cast(v8bf, h0),
                                                   acc0, 0, 0, 0);
    acc1 = __builtin_amdgcn_mfma_f32_16x16x32_bf16(av, __builtin_bit_cast(v8bf, h1),
                                                   acc1, 0, 0, 0);
    acc2 = __builtin_amdgcn_mfma_f32_16x16x32_bf16(av, ones_f, acc2, 0, 0, 0);
  }

  // C/D: col = lane&15, row = kg*4 + r
#pragma unroll
  for (int r = 0; r < 4; ++r) {
    int row = kg * 4 + r;
    atomicAdd(&part[(head * 16 + row) * DK + m], acc0[r]);
    atomicAdd(&part[(head * 16 + row) * DK + 16 + m], acc1[r]);
  }
  if (m == 0) {  // acc2 col 0 holds row sums
#pragma unroll
    for (int r = 0; r < 4; ++r) atomicAdd(&lsh[head * 16 + kg * 4 + r], acc2[r]);
  }
  __syncthreads();

  // 2048 outputs: 512 threads x float4, coalesced
  if (tid < 512) {
    int gd = tid * 4;
    int rh = gd >> 9, ri = (gd >> 5) & 15, rd = gd & 31;
    float inv = 1.0f / lsh[rh * 16 + ri];
    float4 s4 = *(const float4*)&part[(rh * 16 + ri) * DK + rd];
    float4 o = {s4.x * inv, s4.y * inv, s4.z * inv, s4.w * inv};
    *(float4*)&out[(size_t)((b * H + rh) * N + it16 * 16 + ri) * DK + rd] = o;
  }
}

extern "C" void kernel_launch(void* const* d_in, const int* in_sizes, int n_in,
                              void* d_out, int out_size, void* d_ws, size_t ws_size,
                              hipStream_t stream) {
  const float* x = (const float*)d_in[0];
  const int* adj = (const int*)d_in[1];
  const float* W = (const float*)d_in[2];
  const float* a = (const float*)d_in[3];
  float* out = (float*)d_out;
  char* ws = (char*)d_ws;

  unsigned short* h_t = (unsigned short*)(ws);       // 2 MB  [B][H][DK][N]
  float* el = (float*)(ws + 0x200000);               // 128 KB
  float* er = (float*)(ws + 0x220000);               // 128 KB
  unsigned int* adjb = (unsigned int*)(ws + 0x240000);  // 2 MB bitmask

  hipLaunchKernelGGL(k_pack, dim3(B * N * N / 1024), dim3(256), 0, stream, adj, adjb);
  hipLaunchKernelGGL(k_hproj, dim3(B * IT), dim3(256), 0, stream, x, W, a, h_t, el, er);
  hipLaunchKernelGGL(k_attn, dim3(B * (N / 16)), dim3(1024), 0, stream, adjb, h_t, el, er, out);
}